// Round 2
// baseline (1360.130 us; speedup 1.0000x reference)
//
#include <hip/hip_runtime.h>
#include <hip/hip_bf16.h>

// LoRA row-parallel linear on MI355X.
// y[T,N] = x[T,K] @ W[N,K]^T + bias[N] + scale[s]*( x @ A[s]^T ) @ B[s]^T  (s = token slot)
// Strategy: split-bf16 (hi/lo) MFMA GEMM with K-extended segments folding in LoRA-B.
// Segments: x_hi*W_hi | x_lo*W_hi | x_hi*W_lo | u_hi*B_hi | u_lo*B_hi | u_hi*B_lo
// (missing lo*lo terms are ~2^-18 relative — far below fp32 tolerance).

#define T_TOK 8192
#define D_INP 4096
#define D_OUTP 4096
#define N_SLOT 8
#define RANK 16

typedef __attribute__((ext_vector_type(8))) short bf16x8;
typedef __attribute__((ext_vector_type(8))) unsigned short u16x8;
typedef __attribute__((ext_vector_type(4))) float f32x4;

__device__ __forceinline__ unsigned short f2bf_rne(float f) {
  unsigned int u = __float_as_uint(f);
  unsigned int r = u + 0x7fffu + ((u >> 16) & 1u);
  return (unsigned short)(r >> 16);
}
__device__ __forceinline__ float bf2f(unsigned short h) {
  return __uint_as_float(((unsigned int)h) << 16);
}

// ---------------- fp32 -> (hi,lo) bf16 split, 8 elems/thread ----------------
__global__ void k_split(const float* __restrict__ in, unsigned short* __restrict__ hi,
                        unsigned short* __restrict__ lo, int n8) {
  int i = blockIdx.x * blockDim.x + threadIdx.x;
  const int stride = gridDim.x * blockDim.x;
  for (; i < n8; i += stride) {
    const f32x4* p = (const f32x4*)(in) + 2 * (size_t)i;
    f32x4 a = p[0], b = p[1];
    u16x8 h, l;
#pragma unroll
    for (int j = 0; j < 8; ++j) {
      float v = (j < 4) ? a[j] : b[j - 4];
      unsigned short hh = f2bf_rne(v);
      h[j] = hh;
      l[j] = f2bf_rne(v - bf2f(hh));
    }
    *((u16x8*)(hi) + i) = h;
    *((u16x8*)(lo) + i) = l;
  }
}

// ------------- lora_B [S][N][R] -> B_re [N][S*R] bf16 hi/lo ----------------
__global__ void k_bre(const float* __restrict__ B, unsigned short* __restrict__ hi,
                      unsigned short* __restrict__ lo) {
  int e = blockIdx.x * 256 + threadIdx.x;
  if (e >= D_OUTP * 128) return;
  int n = e >> 7, j = e & 127;
  int s = j >> 4, r = j & 15;
  float v = B[((size_t)s * D_OUTP + n) * RANK + r];
  unsigned short h = f2bf_rne(v);
  hi[e] = h;
  lo[e] = f2bf_rne(v - bf2f(h));
}

// ------------- u[t][r] = scale[slot]*sum_k x[t,k]*A[slot,r,k] (fp32 exact) --
__global__ void k_lora_u(const float* __restrict__ x, const int* __restrict__ slot,
                         const float* __restrict__ A, const float* __restrict__ scaling,
                         float* __restrict__ u) {
  const int t = blockIdx.x;
  const int tid = threadIdx.x;
  const int s = slot[t];
  const bool ok = (s >= 0) && (s < N_SLOT);
  __shared__ float red[4][16];
  float acc[16];
#pragma unroll
  for (int r = 0; r < 16; ++r) acc[r] = 0.0f;
  if (ok) {
    const float* xr = x + (size_t)t * D_INP;
    const float* Ab = A + (size_t)s * RANK * D_INP;
#pragma unroll
    for (int kb = 0; kb < 4; ++kb) {
      const int k = (kb * 256 + tid) * 4;
      const f32x4 xv = *(const f32x4*)(xr + k);
#pragma unroll
      for (int r = 0; r < 16; ++r) {
        const f32x4 av = *(const f32x4*)(Ab + (size_t)r * D_INP + k);
        acc[r] += xv[0] * av[0] + xv[1] * av[1] + xv[2] * av[2] + xv[3] * av[3];
      }
    }
  }
#pragma unroll
  for (int r = 0; r < 16; ++r) {
#pragma unroll
    for (int off = 32; off > 0; off >>= 1)
      acc[r] += __shfl_down(acc[r], off, 64);
  }
  const int lane = tid & 63, wv = tid >> 6;
  if (lane == 0) {
#pragma unroll
    for (int r = 0; r < 16; ++r) red[wv][r] = acc[r];
  }
  __syncthreads();
  if (tid < 16) {
    float v = red[0][tid] + red[1][tid] + red[2][tid] + red[3][tid];
    u[(size_t)t * 16 + tid] = ok ? v * scaling[s] : 0.0f;
  }
}

// ------------- u[T][16] -> masked dense [T][S*R] bf16 hi/lo ----------------
__global__ void k_umask(const float* __restrict__ u, const int* __restrict__ slot,
                        unsigned short* __restrict__ uhi, unsigned short* __restrict__ ulo) {
  int e = blockIdx.x * 256 + threadIdx.x;
  if (e >= T_TOK * 128) return;
  int t = e >> 7, j = e & 127;
  int s = slot[t];
  float v = (s == (j >> 4)) ? u[(size_t)t * 16 + (j & 15)] : 0.0f;
  unsigned short h = f2bf_rne(v);
  uhi[e] = h;
  ulo[e] = f2bf_rne(v - bf2f(h));
}

// ---------------- main GEMM: m97-style 128x128, BK=64, swizzled LDS --------
__device__ __forceinline__ void proc_seg(
    const unsigned short* __restrict__ Asrc, const unsigned short* __restrict__ Bsrc,
    const int lda, const int ldb, const int ntiles,
    const int bm, const int bn, const int wave, const int lane,
    const int wr, const int wc,
    unsigned short* __restrict__ Asmem, unsigned short* __restrict__ Bsmem,
    f32x4 (&acc)[4][4])
{
  for (int kt = 0; kt < ntiles; ++kt) {
    const int k0 = kt * 64;
    // stage 128x64 bf16 A-tile + B-tile via global_load_lds (16B/lane).
    // LDS dest is linear (wave-uniform base + lane*16); source column-chunk is
    // pre-swizzled (cc ^= row&7) so swizzled ds_reads see conflict-free banks.
#pragma unroll
    for (int p = 0; p < 4; ++p) {
      const int cb = p * 256 + wave * 64;   // wave-uniform chunk base
      const int c = cb + lane;              // chunk id 0..1023
      const int r = c >> 3;                 // tile row 0..127
      const int scc = (c & 7) ^ (r & 7);    // swizzled source col-chunk
      const unsigned short* ga = Asrc + (size_t)(bm + r) * lda + (k0 + scc * 8);
      const unsigned short* gb = Bsrc + (size_t)(bn + r) * ldb + (k0 + scc * 8);
      __builtin_amdgcn_global_load_lds(
          (const __attribute__((address_space(1))) void*)ga,
          (__attribute__((address_space(3))) void*)((char*)Asmem + cb * 16), 16, 0, 0);
      __builtin_amdgcn_global_load_lds(
          (const __attribute__((address_space(1))) void*)gb,
          (__attribute__((address_space(3))) void*)((char*)Bsmem + cb * 16), 16, 0, 0);
    }
    __syncthreads();  // compiler drains vmcnt(0) before s_barrier
#pragma unroll
    for (int s = 0; s < 2; ++s) {  // two K=32 MFMA steps per BK=64 tile
      bf16x8 af[4], bfr[4];
#pragma unroll
      for (int mi = 0; mi < 4; ++mi) {
        const int ra = wr * 64 + mi * 16 + (lane & 15);
        const int j = s * 4 + (lane >> 4);
        af[mi] = *(const bf16x8*)((const char*)Asmem + ra * 128 + ((j ^ (ra & 7)) << 4));
      }
#pragma unroll
      for (int ni = 0; ni < 4; ++ni) {
        const int rb = wc * 64 + ni * 16 + (lane & 15);
        const int j = s * 4 + (lane >> 4);
        bfr[ni] = *(const bf16x8*)((const char*)Bsmem + rb * 128 + ((j ^ (rb & 7)) << 4));
      }
#pragma unroll
      for (int mi = 0; mi < 4; ++mi)
#pragma unroll
        for (int ni = 0; ni < 4; ++ni)
          acc[mi][ni] = __builtin_amdgcn_mfma_f32_16x16x32_bf16(af[mi], bfr[ni], acc[mi][ni], 0, 0, 0);
    }
    __syncthreads();
  }
}

__global__ __launch_bounds__(256, 2) void k_gemm(
    const unsigned short* __restrict__ xhi, const unsigned short* __restrict__ xlo,
    const unsigned short* __restrict__ whi, const unsigned short* __restrict__ wlo,
    const unsigned short* __restrict__ uhi, const unsigned short* __restrict__ ulo,
    const unsigned short* __restrict__ bhi, const unsigned short* __restrict__ blo,
    const float* __restrict__ bias, float* __restrict__ out)
{
  __shared__ unsigned short Asmem[128 * 64];
  __shared__ unsigned short Bsmem[128 * 64];
  const int tid = threadIdx.x;
  const int lane = tid & 63;
  const int wave = tid >> 6;
  const int wr = wave >> 1, wc = wave & 1;  // 2x2 waves -> 64x64 each

  // XCD-aware bijective swizzle (2048 % 8 == 0)
  const int bid = blockIdx.x;
  const int cpx = gridDim.x >> 3;
  const int swz = (bid & 7) * cpx + (bid >> 3);
  const int tm = swz >> 5;   // 64 M-tiles
  const int tn = swz & 31;   // 32 N-tiles
  const int bm = tm * 128, bn = tn * 128;

  f32x4 acc[4][4] = {};

  // K-extended segments: hi*hi | lo*hi | hi*lo | u_hi*B_hi | u_lo*B_hi | u_hi*B_lo
  proc_seg(xhi, whi, D_INP, D_INP, 64, bm, bn, wave, lane, wr, wc, Asmem, Bsmem, acc);
  proc_seg(xlo, whi, D_INP, D_INP, 64, bm, bn, wave, lane, wr, wc, Asmem, Bsmem, acc);
  proc_seg(xhi, wlo, D_INP, D_INP, 64, bm, bn, wave, lane, wr, wc, Asmem, Bsmem, acc);
  proc_seg(uhi, bhi, 128, 128, 2, bm, bn, wave, lane, wr, wc, Asmem, Bsmem, acc);
  proc_seg(ulo, bhi, 128, 128, 2, bm, bn, wave, lane, wr, wc, Asmem, Bsmem, acc);
  proc_seg(uhi, blo, 128, 128, 2, bm, bn, wave, lane, wr, wc, Asmem, Bsmem, acc);

  // epilogue: + bias, fp32 store. C/D layout: col=lane&15, row=(lane>>4)*4+j
#pragma unroll
  for (int ni = 0; ni < 4; ++ni) {
    const int col = bn + wc * 64 + ni * 16 + (lane & 15);
    const float bv = bias[col];
#pragma unroll
    for (int mi = 0; mi < 4; ++mi) {
      const int row0 = bm + wr * 64 + mi * 16 + (lane >> 4) * 4;
#pragma unroll
      for (int j = 0; j < 4; ++j)
        out[(size_t)(row0 + j) * D_OUTP + col] = acc[mi][ni][j] + bv;
    }
  }
}

// ---------------- fp32 fallback (only if ws too small) ---------------------
__global__ __launch_bounds__(256) void k_fb_gemm(
    const float* __restrict__ x, const float* __restrict__ W,
    const float* __restrict__ bias, const float* __restrict__ u,
    const int* __restrict__ slot, const float* __restrict__ B,
    float* __restrict__ out)
{
  __shared__ float As[64][17];
  __shared__ float Bs[64][17];
  const int bid = blockIdx.x;
  const int bm = (bid >> 6) * 64;
  const int bn = (bid & 63) * 64;
  const int tid = threadIdx.x;
  const int tx = tid & 15, ty = tid >> 4;
  float acc[4][4] = {};
  for (int kt = 0; kt < 256; ++kt) {
    const int k0 = kt * 16;
#pragma unroll
    for (int p = 0; p < 4; ++p) {
      const int c = p * 256 + tid;
      const int rr = c >> 4, ck = c & 15;
      As[rr][ck] = x[(size_t)(bm + rr) * D_INP + k0 + ck];
      Bs[rr][ck] = W[(size_t)(bn + rr) * D_INP + k0 + ck];
    }
    __syncthreads();
#pragma unroll
    for (int kk = 0; kk < 16; ++kk) {
      float av[4], bv[4];
#pragma unroll
      for (int i = 0; i < 4; ++i) av[i] = As[ty * 4 + i][kk];
#pragma unroll
      for (int j = 0; j < 4; ++j) bv[j] = Bs[tx * 4 + j][kk];
#pragma unroll
      for (int i = 0; i < 4; ++i)
#pragma unroll
        for (int j = 0; j < 4; ++j) acc[i][j] += av[i] * bv[j];
    }
    __syncthreads();
  }
#pragma unroll
  for (int i = 0; i < 4; ++i) {
    const int m = bm + ty * 4 + i;
    const int s = slot[m];
#pragma unroll
    for (int j = 0; j < 4; ++j) {
      const int n = bn + tx * 4 + j;
      float v = acc[i][j] + bias[n];
      if (s >= 0 && s < N_SLOT) {
        const float* Bp = B + ((size_t)s * D_OUTP + n) * RANK;
        const float* up = u + (size_t)m * RANK;
        float l = 0.f;
#pragma unroll
        for (int r = 0; r < RANK; ++r) l += up[r] * Bp[r];
        v += l;
      }
      out[(size_t)m * D_OUTP + n] = v;
    }
  }
}

extern "C" void kernel_launch(void* const* d_in, const int* in_sizes, int n_in,
                              void* d_out, int out_size, void* d_ws, size_t ws_size,
                              hipStream_t stream) {
  const float* x      = (const float*)d_in[0];
  const int*   slot   = (const int*)d_in[1];
  const float* W      = (const float*)d_in[2];
  const float* bias   = (const float*)d_in[3];
  const float* lA     = (const float*)d_in[4];
  const float* lB     = (const float*)d_in[5];
  const float* lscale = (const float*)d_in[6];
  float* out = (float*)d_out;

  char* ws = (char*)d_ws;
  const size_t SZ_XH = (size_t)T_TOK * D_INP * 2;   // 64 MB
  const size_t SZ_WH = (size_t)D_OUTP * D_INP * 2;  // 32 MB
  const size_t SZ_UH = (size_t)T_TOK * 128 * 2;     // 2 MB
  const size_t SZ_BH = (size_t)D_OUTP * 128 * 2;    // 1 MB
  const size_t SZ_U32 = (size_t)T_TOK * 16 * 4;     // 512 KB
  size_t off = 0;
  unsigned short* xhi = (unsigned short*)(ws + off); off += SZ_XH;
  unsigned short* xlo = (unsigned short*)(ws + off); off += SZ_XH;
  unsigned short* whi = (unsigned short*)(ws + off); off += SZ_WH;
  unsigned short* wlo = (unsigned short*)(ws + off); off += SZ_WH;
  unsigned short* uhi = (unsigned short*)(ws + off); off += SZ_UH;
  unsigned short* ulo = (unsigned short*)(ws + off); off += SZ_UH;
  unsigned short* bhi = (unsigned short*)(ws + off); off += SZ_BH;
  unsigned short* blo = (unsigned short*)(ws + off); off += SZ_BH;
  float* u32 = (float*)(ws + off); off += SZ_U32;

  if (ws_size >= off) {
    k_split<<<2048, 256, 0, stream>>>(x, xhi, xlo, (int)((size_t)T_TOK * D_INP / 8));
    k_split<<<1024, 256, 0, stream>>>(W, whi, wlo, (int)((size_t)D_OUTP * D_INP / 8));
    k_bre<<<(D_OUTP * 128) / 256, 256, 0, stream>>>(lB, bhi, blo);
    k_lora_u<<<T_TOK, 256, 0, stream>>>(x, slot, lA, lscale, u32);
    k_umask<<<(T_TOK * 128) / 256, 256, 0, stream>>>(u32, slot, uhi, ulo);
    k_gemm<<<2048, 256, 0, stream>>>(xhi, xlo, whi, wlo, uhi, ulo, bhi, blo, bias, out);
  } else {
    // workspace too small for split path: exact fp32 fallback
    float* u32b = (float*)ws;
    k_lora_u<<<T_TOK, 256, 0, stream>>>(x, slot, lA, lscale, u32b);
    k_fb_gemm<<<(T_TOK / 64) * (D_OUTP / 64), 256, 0, stream>>>(x, W, bias, u32b, slot, lB, out);
  }
}